// Round 10
// baseline (1265.218 us; speedup 1.0000x reference)
//
#include <hip/hip_runtime.h>
#include <hip/hip_bf16.h>
#include <stdint.h>

// ---------------------------------------------------------------------------
// SwiGLU + int8 weight-quant emulation (VNNILinear), MI355X gfx950. Round 10:
//   Both GEMMs: 2 K-tiles per barrier period. Within a period, reads hit
//   slots {s0,s1} while staging writes slots {s2,s3} (tile&3 ring) -> the
//   mid-period seam needs NO barrier / NO vm-wait, only counted lgkm(6).
//   One {lgkm0 -> vm0 -> BAR} per 2 tiles. Main loop unrolled 2 periods
//   (compile-time slot offsets); generic 2-period tail.
//   Preproc: single-pass (row kept in registers; saves one full input read).
//   R9 PM: per-tile sync slack (not pipe throughput) dominates; 2 waves/SIMD
//   is a hard register wall (acc 128 AGPR + ~124 VGPR), so cut sync points.
// ---------------------------------------------------------------------------

typedef short bf16x8 __attribute__((ext_vector_type(8)));
typedef float f32x4  __attribute__((ext_vector_type(4)));
typedef float f32x16 __attribute__((ext_vector_type(16)));
typedef int   i32x4  __attribute__((ext_vector_type(4)));
typedef int   i32x16 __attribute__((ext_vector_type(16)));

__device__ __forceinline__ unsigned short f2bf(float f) {
  unsigned u = __builtin_bit_cast(unsigned, f);
  u += 0x7FFFu + ((u >> 16) & 1u);   // RNE
  return (unsigned short)(u >> 16);
}

#define GLOAD_LDS16(gaddr, laddr)                                             \
  __builtin_amdgcn_global_load_lds(                                           \
      (const __attribute__((address_space(1))) void*)(gaddr),                 \
      (__attribute__((address_space(3))) void*)(laddr), 16, 0, 0)

#define FENCE()      asm volatile("" ::: "memory")
#define BAR()        __builtin_amdgcn_s_barrier()
#define WAIT_LGKM(n) asm volatile("s_waitcnt lgkmcnt(" #n ")" ::: "memory")
#define WAIT_VM0()   asm volatile("s_waitcnt vmcnt(0)" ::: "memory")
#define SFENCE()     __builtin_amdgcn_sched_barrier(0)
#define PRIO1()      __builtin_amdgcn_s_setprio(1)
#define PRIO0()      __builtin_amdgcn_s_setprio(0)

// --------------------------- preprocessing --------------------------------
// Single-pass: row lives in registers; max-reduce then quantize, one read.

template <int NCH>   // cols = NCH*1024, 256 threads
__global__ void quant_rows_i8_sp(const float* __restrict__ w,
                                 char* __restrict__ q,
                                 float* __restrict__ scale, float clip) {
  const int cols = NCH * 1024;
  const float* wr = w + (size_t)blockIdx.x * cols;
  char* qr = q + (size_t)blockIdx.x * cols;

  float4 v[NCH];
  float m = 0.f;
#pragma unroll
  for (int j = 0; j < NCH; ++j) {
    v[j] = *reinterpret_cast<const float4*>(wr + threadIdx.x * 4 + j * 1024);
    m = fmaxf(m, fmaxf(fmaxf(fabsf(v[j].x), fabsf(v[j].y)),
                       fmaxf(fabsf(v[j].z), fabsf(v[j].w))));
  }
#pragma unroll
  for (int off = 32; off; off >>= 1) m = fmaxf(m, __shfl_xor(m, off));
  __shared__ float smax[4];
  if ((threadIdx.x & 63) == 0) smax[threadIdx.x >> 6] = m;
  __syncthreads();
  m = fmaxf(fmaxf(smax[0], smax[1]), fmaxf(smax[2], smax[3]));

  const float s = fmaxf(m, clip) / 127.0f;
  if (threadIdx.x == 0) scale[blockIdx.x] = s;
#pragma unroll
  for (int j = 0; j < NCH; ++j) {
    int b0 = (int)rintf(v[j].x / s), b1 = (int)rintf(v[j].y / s);
    int b2 = (int)rintf(v[j].z / s), b3 = (int)rintf(v[j].w / s);
    unsigned pk = (b0 & 0xff) | ((b1 & 0xff) << 8) | ((b2 & 0xff) << 16)
                  | ((b3 & 0xff) << 24);
    *reinterpret_cast<unsigned*>(qr + threadIdx.x * 4 + j * 1024) = pk;
  }
}

template <int NCH>
__global__ void quant_rows_bf16_sp(const float* __restrict__ w,
                                   unsigned short* __restrict__ wq) {
  const int cols = NCH * 1024;
  const float* wr = w + (size_t)blockIdx.x * cols;
  unsigned short* wqr = wq + (size_t)blockIdx.x * cols;

  float4 v[NCH];
  float m = 0.f;
#pragma unroll
  for (int j = 0; j < NCH; ++j) {
    v[j] = *reinterpret_cast<const float4*>(wr + threadIdx.x * 4 + j * 1024);
    m = fmaxf(m, fmaxf(fmaxf(fabsf(v[j].x), fabsf(v[j].y)),
                       fmaxf(fabsf(v[j].z), fabsf(v[j].w))));
  }
#pragma unroll
  for (int off = 32; off; off >>= 1) m = fmaxf(m, __shfl_xor(m, off));
  __shared__ float smax[4];
  if ((threadIdx.x & 63) == 0) smax[threadIdx.x >> 6] = m;
  __syncthreads();
  m = fmaxf(fmaxf(smax[0], smax[1]), fmaxf(smax[2], smax[3]));

  const float s = fmaxf(m, 1e-6f) / 127.0f;
#pragma unroll
  for (int j = 0; j < NCH; ++j) {
    ushort4 o;
    o.x = f2bf(rintf(v[j].x / s) * s);
    o.y = f2bf(rintf(v[j].y / s) * s);
    o.z = f2bf(rintf(v[j].z / s) * s);
    o.w = f2bf(rintf(v[j].w / s) * s);
    *reinterpret_cast<ushort4*>(wqr + threadIdx.x * 4 + j * 1024) = o;
  }
}

// ------------------------------ GEMMs -------------------------------------

__device__ __forceinline__ void xcd_swizzle(int& bx, int& by, int gx, int gy) {
  int nwg = gx * gy;              // both grids are % 8 == 0
  int bid = by * gx + bx;
  int cpx = nwg >> 3;
  int s = (bid & 7) * cpx + (bid >> 3);
  by = s / gx;
  bx = s % gx;
}

// Fused int8 GEMM: H = silu((xq@w1q^T)*sx*sw1) * ((xq@w3q^T)*sx*sw3), bf16.
// Tile 256x128, BK=64, 8 waves (2M x 4N). LDS slot (32 KiB): A 256x64B,
// B1 128x64B @+16K, B3 @+24K. Stored chunk = q ^ ((r>>1)&3) [R7 floor].
__global__ __launch_bounds__(512, 2)
void gemm_i8_swiglu_kernel(const char* __restrict__ Aq,
                           const char* __restrict__ B1q,
                           const char* __restrict__ B3q,
                           const float* __restrict__ sx,
                           const float* __restrict__ sw1,
                           const float* __restrict__ sw3,
                           unsigned short* __restrict__ H,
                           int M, int N, int K) {
  __shared__ alignas(1024) char lds[131072];   // 4 slots x 32 KiB

  int bx = blockIdx.x, by = blockIdx.y;
  xcd_swizzle(bx, by, gridDim.x, gridDim.y);
  const int brow = by * 256, bcol = bx * 128;

  const int t = threadIdx.x, lane = t & 63, w = t >> 6;
  const int wr = w >> 2, wc = w & 3;
  const int l31 = lane & 31, hi = lane >> 5;
  const int NT = K >> 6;   // BK=64; NT=64 here (multiple of 4, >=8)

  const int rS = t >> 2;
  const int gcS = ((t & 3) ^ ((t >> 3) & 3)) * 16;
  const char* srcA  = Aq  + (size_t)(brow + rS) * K + gcS;
  const char* srcB1 = B1q + (size_t)(bcol + rS) * K + gcS;
  const char* srcB3 = B3q + (size_t)(bcol + rS) * K + gcS;

// stage tile kt into slot pointer sp (4 DMA: A lower/upper, B1, B3)
#define STAGE_FT(sp, kt)                                                      \
  {                                                                           \
    const size_t ko = (size_t)(kt) * 64;                                      \
    GLOAD_LDS16(srcA + ko, (sp) + t * 16);                                    \
    GLOAD_LDS16(srcA + (size_t)128 * K + ko, (sp) + 8192 + t * 16);           \
    GLOAD_LDS16(srcB1 + ko, (sp) + 16384 + t * 16);                          \
    GLOAD_LDS16(srcB3 + ko, (sp) + 24576 + t * 16);                          \
  }

  const int sx2 = (l31 >> 1) & 3;
  const int aoff  = (wr * 128 + l31) * 64 + ((hi ^ sx2) * 16);
  const int boff1 = 16384 + (wc * 32 + l31) * 64 + ((hi ^ sx2) * 16);
  const int boff3 = boff1 + 8192;

// load one frag set (4 A + 2 B reads) from slot base, kh via xr (0 or ^32)
#define LOADSET_F(aa, bb1, bb3, base, xr)                                     \
  aa[0] = *reinterpret_cast<const i32x4*>((base) + (aoff ^ (xr)));            \
  aa[1] = *reinterpret_cast<const i32x4*>((base) + (aoff ^ (xr)) + 2048);     \
  aa[2] = *reinterpret_cast<const i32x4*>((base) + (aoff ^ (xr)) + 4096);     \
  aa[3] = *reinterpret_cast<const i32x4*>((base) + (aoff ^ (xr)) + 6144);     \
  bb1 = *reinterpret_cast<const i32x4*>((base) + (boff1 ^ (xr)));             \
  bb3 = *reinterpret_cast<const i32x4*>((base) + (boff3 ^ (xr)));

  i32x16 acc[4][2] = {};
  i32x4 a0[4], b10, b30;
  i32x4 a1[4], b11, b31;

#define MFMA8_F(ar, b1r, b3r)                                                 \
  acc[0][0] = __builtin_amdgcn_mfma_i32_32x32x32_i8(ar[0], b1r, acc[0][0], 0, 0, 0); \
  acc[0][1] = __builtin_amdgcn_mfma_i32_32x32x32_i8(ar[0], b3r, acc[0][1], 0, 0, 0); \
  acc[1][0] = __builtin_amdgcn_mfma_i32_32x32x32_i8(ar[1], b1r, acc[1][0], 0, 0, 0); \
  acc[1][1] = __builtin_amdgcn_mfma_i32_32x32x32_i8(ar[1], b3r, acc[1][1], 0, 0, 0); \
  acc[2][0] = __builtin_amdgcn_mfma_i32_32x32x32_i8(ar[2], b1r, acc[2][0], 0, 0, 0); \
  acc[2][1] = __builtin_amdgcn_mfma_i32_32x32x32_i8(ar[2], b3r, acc[2][1], 0, 0, 0); \
  acc[3][0] = __builtin_amdgcn_mfma_i32_32x32x32_i8(ar[3], b1r, acc[3][0], 0, 0, 0); \
  acc[3][1] = __builtin_amdgcn_mfma_i32_32x32x32_i8(ar[3], b3r, acc[3][1], 0, 0, 0)

// one period: tiles t0 (slot base S0) and t0+1 (S1); staging handled outside
#define PERIOD_CORE_F(S0, S1)                                                 \
  WAIT_LGKM(6); SFENCE();                                                     \
  PRIO1(); MFMA8_F(a0, b10, b30); PRIO0();                                    \
  LOADSET_F(a0, b10, b30, (S1), 0);                                           \
  WAIT_LGKM(6); SFENCE();                                                     \
  PRIO1(); MFMA8_F(a1, b11, b31); PRIO0();                                    \
  LOADSET_F(a1, b11, b31, (S1), 32);                                          \
  WAIT_LGKM(6); SFENCE();                                                     \
  PRIO1(); MFMA8_F(a0, b10, b30); PRIO0();                                    \
  WAIT_LGKM(0); WAIT_VM0(); FENCE(); BAR();

  // prologue: stage tiles 0,1; preload set0 of tile 0
  STAGE_FT(lds, 0);
  STAGE_FT(lds + 32768, 1);
  WAIT_VM0(); FENCE(); BAR();
  LOADSET_F(a0, b10, b30, lds, 0);

  int kb = 0;
  for (; kb + 6 <= NT; kb += 4) {
    // ---- even period: tiles kb,kb+1 in slots 0,1; stage kb+2,kb+3 -> 2,3
    LOADSET_F(a1, b11, b31, lds, 32);
    STAGE_FT(lds + 65536, kb + 2);
    STAGE_FT(lds + 98304, kb + 3);
    PERIOD_CORE_F(lds, lds + 32768);
    LOADSET_F(a0, b10, b30, lds + 65536, 0);
    SFENCE();
    PRIO1(); MFMA8_F(a1, b11, b31); PRIO0();

    // ---- odd period: tiles kb+2,kb+3 in slots 2,3; stage kb+4,kb+5 -> 0,1
    LOADSET_F(a1, b11, b31, lds + 65536, 32);
    STAGE_FT(lds, kb + 4);
    STAGE_FT(lds + 32768, kb + 5);
    PERIOD_CORE_F(lds + 65536, lds + 98304);
    LOADSET_F(a0, b10, b30, lds, 0);
    SFENCE();
    PRIO1(); MFMA8_F(a1, b11, b31); PRIO0();
  }

  // ---- tail: generic periods (at most 2), staging conditional ----
  for (int t0 = kb; t0 < NT; t0 += 2) {
    const char* s0p = lds + (t0 & 3) * 32768;
    const char* s1p = lds + ((t0 + 1) & 3) * 32768;
    LOADSET_F(a1, b11, b31, s0p, 32);
    if (t0 + 3 < NT) {
      STAGE_FT(lds + ((t0 + 2) & 3) * 32768, t0 + 2);
      STAGE_FT(lds + ((t0 + 3) & 3) * 32768, t0 + 3);
    }
    PERIOD_CORE_F(s0p, s1p);
    if (t0 + 2 < NT) {
      LOADSET_F(a0, b10, b30, lds + ((t0 + 2) & 3) * 32768, 0);
    }
    SFENCE();
    PRIO1(); MFMA8_F(a1, b11, b31); PRIO0();
  }
#undef PERIOD_CORE_F
#undef MFMA8_F
#undef LOADSET_F
#undef STAGE_FT

  // ---- epilogue: dequant + SwiGLU -> bf16 (verified R4-R9) ----
  const int ocol = bcol + wc * 32 + l31;
  const int rowb = brow + wr * 128 + 4 * hi;
  const float sw1c = sw1[ocol], sw3c = sw3[ocol];
#pragma unroll
  for (int m = 0; m < 4; ++m) {
#pragma unroll
    for (int rq = 0; rq < 4; ++rq) {
      const int r0 = rowb + m * 32 + 8 * rq;
      const f32x4 sx4 = *reinterpret_cast<const f32x4*>(sx + r0);
#pragma unroll
      for (int j = 0; j < 4; ++j) {
        float y1 = (float)acc[m][0][rq * 4 + j] * (sx4[j] * sw1c);
        float y3 = (float)acc[m][1][rq * 4 + j] * (sx4[j] * sw3c);
        float hv = (y1 / (1.f + __expf(-y1))) * y3;
        H[(size_t)(r0 + j) * N + ocol] = f2bf(hv);
      }
    }
  }
}

// bf16 GEMM: C = A @ B^T (fp32 out). Tile 256x256, BK=32, 32x32x16 MFMA,
// same 2-tile-period skeleton. Stored chunk = q ^ ((r>>1)&3).
__global__ __launch_bounds__(512, 2)
void gemm_bf16_kernel(const unsigned short* __restrict__ A,
                      const unsigned short* __restrict__ B,
                      float* __restrict__ C, int M, int N, int K) {
  __shared__ alignas(1024) unsigned short lds[65536];  // 4 slots x 32 KiB

  int bx = blockIdx.x, by = blockIdx.y;
  xcd_swizzle(bx, by, gridDim.x, gridDim.y);
  const int brow = by * 256, bcol = bx * 256;

  const int t = threadIdx.x, lane = t & 63, w = t >> 6;
  const int wr = w >> 2, wc = w & 3;
  const int l31 = lane & 31, hi = lane >> 5;
  const int NT = K >> 5;   // BK=32; NT=256

  const int rS = t >> 2;
  const int cS = ((t & 3) ^ ((t >> 3) & 3)) * 8;   // sh units
  const unsigned short* srcA = A + (size_t)(brow + rS) * K + cS;
  const unsigned short* srcB = B + (size_t)(bcol + rS) * K + cS;

#define STAGE_GT(sp, kt)                                                      \
  {                                                                           \
    const size_t ko = (size_t)(kt) * 32;                                      \
    GLOAD_LDS16(srcA + ko, (sp) + t * 8);                                     \
    GLOAD_LDS16(srcA + (size_t)128 * K + ko, (sp) + 4096 + t * 8);            \
    GLOAD_LDS16(srcB + ko, (sp) + 8192 + t * 8);                              \
    GLOAD_LDS16(srcB + (size_t)128 * K + ko, (sp) + 12288 + t * 8);           \
  }

  const int sx2 = (l31 >> 1) & 3;
  const int aoff  = (wr * 128 + l31) * 32 + ((hi ^ sx2) * 8);
  const int boff0 = 8192 + (wc * 64 + l31) * 32 + ((hi ^ sx2) * 8);
  const int boff1b = boff0 + 1024;

#define LOADSET_G(aa, bb0, bb1, base, xr)                                     \
  aa[0] = *reinterpret_cast<const bf16x8*>((base) + (aoff ^ (xr)));           \
  aa[1] = *reinterpret_cast<const bf16x8*>((base) + (aoff ^ (xr)) + 1024);    \
  aa[2] = *reinterpret_cast<const bf16x8*>((base) + (aoff ^ (xr)) + 2048);    \
  aa[3] = *reinterpret_cast<const bf16x8*>((base) + (aoff ^ (xr)) + 3072);    \
  bb0 = *reinterpret_cast<const bf16x8*>((base) + (boff0 ^ (xr)));            \
  bb1 = *reinterpret_cast<const bf16x8*>((base) + (boff1b ^ (xr)));

  f32x16 acc[4][2] = {};
  bf16x8 a0[4], b00, b01;
  bf16x8 a1[4], b10, b11;

#define MFMA8_G(ar, bx0, bx1)                                                 \
  acc[0][0] = __builtin_amdgcn_mfma_f32_32x32x16_bf16(ar[0], bx0, acc[0][0], 0, 0, 0); \
  acc[0][1] = __builtin_amdgcn_mfma_f32_32x32x16_bf16(ar[0], bx1, acc[0][1], 0, 0, 0); \
  acc[1][0] = __builtin_amdgcn_mfma_f32_32x32x16_bf16(ar[1], bx0, acc[1][0], 0, 0, 0); \
  acc[1][1] = __builtin_amdgcn_mfma_f32_32x32x16_bf16(ar[1], bx1, acc[1][1], 0, 0, 0); \
  acc[2][0] = __builtin_amdgcn_mfma_f32_32x32x16_bf16(ar[2], bx0, acc[2][0], 0, 0, 0); \
  acc[2][1] = __builtin_amdgcn_mfma_f32_32x32x16_bf16(ar[2], bx1, acc[2][1], 0, 0, 0); \
  acc[3][0] = __builtin_amdgcn_mfma_f32_32x32x16_bf16(ar[3], bx0, acc[3][0], 0, 0, 0); \
  acc[3][1] = __builtin_amdgcn_mfma_f32_32x32x16_bf16(ar[3], bx1, acc[3][1], 0, 0, 0)

#define PERIOD_CORE_G(S0, S1)                                                 \
  WAIT_LGKM(6); SFENCE();                                                     \
  PRIO1(); MFMA8_G(a0, b00, b01); PRIO0();                                    \
  LOADSET_G(a0, b00, b01, (S1), 0);                                           \
  WAIT_LGKM(6); SFENCE();                                                     \
  PRIO1(); MFMA8_G(a1, b10, b11); PRIO0();                                    \
  LOADSET_G(a1, b10, b11, (S1), 16);                                          \
  WAIT_LGKM(6); SFENCE();                                                     \
  PRIO1(); MFMA8_G(a0, b00, b01); PRIO0();                                    \
  WAIT_LGKM(0); WAIT_VM0(); FENCE(); BAR();

  STAGE_GT(lds, 0);
  STAGE_GT(lds + 16384, 1);
  WAIT_VM0(); FENCE(); BAR();
  LOADSET_G(a0, b00, b01, lds, 0);

  int kb = 0;
  for (; kb + 6 <= NT; kb += 4) {
    // even period: tiles kb,kb+1 (slots 0,1); stage kb+2,kb+3 -> slots 2,3
    LOADSET_G(a1, b10, b11, lds, 16);
    STAGE_GT(lds + 32768, kb + 2);
    STAGE_GT(lds + 49152, kb + 3);
    PERIOD_CORE_G(lds, lds + 16384);
    LOADSET_G(a0, b00, b01, lds + 32768, 0);
    SFENCE();
    PRIO1(); MFMA8_G(a1, b10, b11); PRIO0();

    // odd period: tiles kb+2,kb+3 (slots 2,3); stage kb+4,kb+5 -> slots 0,1
    LOADSET_G(a1, b10, b11, lds + 32768, 16);
    STAGE_GT(lds, kb + 4);
    STAGE_GT(lds + 16384, kb + 5);
    PERIOD_CORE_G(lds + 32768, lds + 49152);
    LOADSET_G(a0, b00, b01, lds, 0);
    SFENCE();
    PRIO1(); MFMA8_G(a1, b10, b11); PRIO0();
  }

  for (int t0 = kb; t0 < NT; t0 += 2) {
    const unsigned short* s0p = lds + (t0 & 3) * 16384;
    const unsigned short* s1p = lds + ((t0 + 1) & 3) * 16384;
    LOADSET_G(a1, b10, b11, s0p, 16);
    if (t0 + 3 < NT) {
      STAGE_GT(lds + ((t0 + 2) & 3) * 16384, t0 + 2);
      STAGE_GT(lds + ((t0 + 3) & 3) * 16384, t0 + 3);
    }
    PERIOD_CORE_G(s0p, s1p);
    if (t0 + 2 < NT) {
      LOADSET_G(a0, b00, b01, lds + ((t0 + 2) & 3) * 16384, 0);
    }
    SFENCE();
    PRIO1(); MFMA8_G(a1, b10, b11); PRIO0();
  }
#undef PERIOD_CORE_G
#undef MFMA8_G
#undef LOADSET_G
#undef STAGE_GT

  const int ocol = bcol + wc * 64 + l31;
  const int rowb = brow + wr * 128 + 4 * hi;
#pragma unroll
  for (int m = 0; m < 4; ++m)
#pragma unroll
    for (int n = 0; n < 2; ++n)
#pragma unroll
      for (int rq = 0; rq < 4; ++rq)
#pragma unroll
        for (int j = 0; j < 4; ++j)
          C[(size_t)(rowb + m * 32 + 8 * rq + j) * N + (ocol + n * 32)] =
              acc[m][n][rq * 4 + j];
}

// ------------------------------ launch -------------------------------------

extern "C" void kernel_launch(void* const* d_in, const int* in_sizes, int n_in,
                              void* d_out, int out_size, void* d_ws,
                              size_t ws_size, hipStream_t stream) {
  const float* x  = (const float*)d_in[0];
  const float* w1 = (const float*)d_in[1];
  const float* w2 = (const float*)d_in[2];
  const float* w3 = (const float*)d_in[3];
  float* out = (float*)d_out;

  const int DIM = 4096, HID = 8192;
  const int M = in_sizes[0] / DIM;  // 8192

  char* xq  = (char*)d_ws;                              // M*DIM    (32 MB)
  char* w1q = xq + (size_t)M * DIM;                     // HID*DIM  (32 MB)
  char* w3q = w1q + (size_t)HID * DIM;                  // HID*DIM  (32 MB)
  unsigned short* w2b = (unsigned short*)(w3q + (size_t)HID * DIM);  // 64 MB
  unsigned short* h = w2b + (size_t)DIM * HID;          // M*HID bf16 (128 MB)
  float* sx  = (float*)(h + (size_t)M * HID);           // M
  float* sw1 = sx + M;                                  // HID
  float* sw3 = sw1 + HID;                               // HID

  quant_rows_i8_sp<4><<<HID, 256, 0, stream>>>(w1, w1q, sw1, 1e-6f);
  quant_rows_i8_sp<4><<<HID, 256, 0, stream>>>(w3, w3q, sw3, 1e-6f);
  quant_rows_i8_sp<4><<<M, 256, 0, stream>>>(x, xq, sx, 1e-30f);
  quant_rows_bf16_sp<8><<<DIM, 256, 0, stream>>>(w2, w2b);

  gemm_i8_swiglu_kernel<<<dim3(HID / 128, M / 256), 512, 0, stream>>>(
      xq, w1q, w3q, sx, sw1, sw3, h, M, HID, DIM);
  gemm_bf16_kernel<<<dim3(DIM / 256, M / 256), 512, 0, stream>>>(
      h, w2b, out, M, DIM, HID);
}

// Round 11
// 1216.735 us; speedup vs baseline: 1.0398x; 1.0398x over previous
//
#include <hip/hip_runtime.h>
#include <hip/hip_bf16.h>
#include <stdint.h>

// ---------------------------------------------------------------------------
// SwiGLU + int8 weight-quant emulation (VNNILinear), MI355X gfx950. Round 11:
//   R9 skeleton (best measured) + wave phase-stagger:
//     - odd waves process kh halves in opposite order (khx XOR on frag offs)
//     - odd waves stage B in P1 / A in P2 (even waves the reverse)
//   Goal: half the waves read LDS while the other half MFMAs (R9 PM: LDS
//   pipe only 54% busy due to barrier phase-coherence).
//   Preproc: single-pass register-resident quant (R10, kept).
// ---------------------------------------------------------------------------

typedef short bf16x8 __attribute__((ext_vector_type(8)));
typedef float f32x4  __attribute__((ext_vector_type(4)));
typedef float f32x16 __attribute__((ext_vector_type(16)));
typedef int   i32x4  __attribute__((ext_vector_type(4)));
typedef int   i32x16 __attribute__((ext_vector_type(16)));

__device__ __forceinline__ unsigned short f2bf(float f) {
  unsigned u = __builtin_bit_cast(unsigned, f);
  u += 0x7FFFu + ((u >> 16) & 1u);   // RNE
  return (unsigned short)(u >> 16);
}

#define GLOAD_LDS16(gaddr, laddr)                                             \
  __builtin_amdgcn_global_load_lds(                                           \
      (const __attribute__((address_space(1))) void*)(gaddr),                 \
      (__attribute__((address_space(3))) void*)(laddr), 16, 0, 0)

#define FENCE()      asm volatile("" ::: "memory")
#define BAR()        __builtin_amdgcn_s_barrier()
#define WAIT_LGKM(n) asm volatile("s_waitcnt lgkmcnt(" #n ")" ::: "memory")
#define WAIT_VM8()   asm volatile("s_waitcnt vmcnt(8)" ::: "memory")
#define WAIT_VM4()   asm volatile("s_waitcnt vmcnt(4)" ::: "memory")
#define WAIT_VM0()   asm volatile("s_waitcnt vmcnt(0)" ::: "memory")
#define SFENCE()     __builtin_amdgcn_sched_barrier(0)
#define PRIO1()      __builtin_amdgcn_s_setprio(1)
#define PRIO0()      __builtin_amdgcn_s_setprio(0)

// --------------------------- preprocessing --------------------------------
// Single-pass: row lives in registers; max-reduce then quantize, one read.

template <int NCH>   // cols = NCH*1024, 256 threads
__global__ void quant_rows_i8_sp(const float* __restrict__ w,
                                 char* __restrict__ q,
                                 float* __restrict__ scale, float clip) {
  const int cols = NCH * 1024;
  const float* wr = w + (size_t)blockIdx.x * cols;
  char* qr = q + (size_t)blockIdx.x * cols;

  float4 v[NCH];
  float m = 0.f;
#pragma unroll
  for (int j = 0; j < NCH; ++j) {
    v[j] = *reinterpret_cast<const float4*>(wr + threadIdx.x * 4 + j * 1024);
    m = fmaxf(m, fmaxf(fmaxf(fabsf(v[j].x), fabsf(v[j].y)),
                       fmaxf(fabsf(v[j].z), fabsf(v[j].w))));
  }
#pragma unroll
  for (int off = 32; off; off >>= 1) m = fmaxf(m, __shfl_xor(m, off));
  __shared__ float smax[4];
  if ((threadIdx.x & 63) == 0) smax[threadIdx.x >> 6] = m;
  __syncthreads();
  m = fmaxf(fmaxf(smax[0], smax[1]), fmaxf(smax[2], smax[3]));

  const float s = fmaxf(m, clip) / 127.0f;
  if (threadIdx.x == 0) scale[blockIdx.x] = s;
#pragma unroll
  for (int j = 0; j < NCH; ++j) {
    int b0 = (int)rintf(v[j].x / s), b1 = (int)rintf(v[j].y / s);
    int b2 = (int)rintf(v[j].z / s), b3 = (int)rintf(v[j].w / s);
    unsigned pk = (b0 & 0xff) | ((b1 & 0xff) << 8) | ((b2 & 0xff) << 16)
                  | ((b3 & 0xff) << 24);
    *reinterpret_cast<unsigned*>(qr + threadIdx.x * 4 + j * 1024) = pk;
  }
}

template <int NCH>
__global__ void quant_rows_bf16_sp(const float* __restrict__ w,
                                   unsigned short* __restrict__ wq) {
  const int cols = NCH * 1024;
  const float* wr = w + (size_t)blockIdx.x * cols;
  unsigned short* wqr = wq + (size_t)blockIdx.x * cols;

  float4 v[NCH];
  float m = 0.f;
#pragma unroll
  for (int j = 0; j < NCH; ++j) {
    v[j] = *reinterpret_cast<const float4*>(wr + threadIdx.x * 4 + j * 1024);
    m = fmaxf(m, fmaxf(fmaxf(fabsf(v[j].x), fabsf(v[j].y)),
                       fmaxf(fabsf(v[j].z), fabsf(v[j].w))));
  }
#pragma unroll
  for (int off = 32; off; off >>= 1) m = fmaxf(m, __shfl_xor(m, off));
  __shared__ float smax[4];
  if ((threadIdx.x & 63) == 0) smax[threadIdx.x >> 6] = m;
  __syncthreads();
  m = fmaxf(fmaxf(smax[0], smax[1]), fmaxf(smax[2], smax[3]));

  const float s = fmaxf(m, 1e-6f) / 127.0f;
#pragma unroll
  for (int j = 0; j < NCH; ++j) {
    ushort4 o;
    o.x = f2bf(rintf(v[j].x / s) * s);
    o.y = f2bf(rintf(v[j].y / s) * s);
    o.z = f2bf(rintf(v[j].z / s) * s);
    o.w = f2bf(rintf(v[j].w / s) * s);
    *reinterpret_cast<ushort4*>(wqr + threadIdx.x * 4 + j * 1024) = o;
  }
}

// ------------------------------ GEMMs -------------------------------------

__device__ __forceinline__ void xcd_swizzle(int& bx, int& by, int gx, int gy) {
  int nwg = gx * gy;              // both grids are % 8 == 0
  int bid = by * gx + bx;
  int cpx = nwg >> 3;
  int s = (bid & 7) * cpx + (bid >> 3);
  by = s / gx;
  bx = s % gx;
}

// Fused int8 GEMM: H = silu((xq@w1q^T)*sx*sw1) * ((xq@w3q^T)*sx*sw3), bf16.
// Tile 256x128, BK=64, 8 waves (2M x 4N), wave tile 128 rows x 32 dual-cols.
// LDS slot (32 KiB): A 256x64B [0,16K), B1 128x64B [16K,24K), B3 [24K,32K).
// Stored chunk = q ^ ((r>>1)&3). R9 schedule + wave kh/stage stagger.
__global__ __launch_bounds__(512, 2)
void gemm_i8_swiglu_kernel(const char* __restrict__ Aq,
                           const char* __restrict__ B1q,
                           const char* __restrict__ B3q,
                           const float* __restrict__ sx,
                           const float* __restrict__ sw1,
                           const float* __restrict__ sw3,
                           unsigned short* __restrict__ H,
                           int M, int N, int K) {
  __shared__ alignas(1024) char lds[131072];   // 4 slots x 32 KiB

  int bx = blockIdx.x, by = blockIdx.y;
  xcd_swizzle(bx, by, gridDim.x, gridDim.y);
  const int brow = by * 256, bcol = bx * 128;

  const int t = threadIdx.x, lane = t & 63, w = t >> 6;
  const int wr = w >> 2, wc = w & 3;
  const int l31 = lane & 31, hi = lane >> 5;
  const bool wodd = (w & 1);
  const int NT = K >> 6;   // BK=64

  const int rS = t >> 2;
  const int gcS = ((t & 3) ^ ((t >> 3) & 3)) * 16;
  const char* srcA  = Aq  + (size_t)(brow + rS) * K + gcS;
  const char* srcB1 = B1q + (size_t)(bcol + rS) * K + gcS;
  const char* srcB3 = B3q + (size_t)(bcol + rS) * K + gcS;

// per-wave parity staging: half the waves issue A-DMAs here, half B-DMAs
#define STAGE_P1(pA_, pB1_, pB3_, sp, ko)                                     \
  if (!wodd) {                                                                \
    GLOAD_LDS16((pA_) + (ko), (sp) + t * 16);                                 \
    GLOAD_LDS16((pA_) + (size_t)128 * K + (ko), (sp) + 8192 + t * 16);        \
  } else {                                                                    \
    GLOAD_LDS16((pB1_) + (ko), (sp) + 16384 + t * 16);                        \
    GLOAD_LDS16((pB3_) + (ko), (sp) + 24576 + t * 16);                        \
  }
#define STAGE_P2(pA_, pB1_, pB3_, sp, ko)                                     \
  if (wodd) {                                                                 \
    GLOAD_LDS16((pA_) + (ko), (sp) + t * 16);                                 \
    GLOAD_LDS16((pA_) + (size_t)128 * K + (ko), (sp) + 8192 + t * 16);        \
  } else {                                                                    \
    GLOAD_LDS16((pB1_) + (ko), (sp) + 16384 + t * 16);                        \
    GLOAD_LDS16((pB3_) + (ko), (sp) + 24576 + t * 16);                        \
  }

  // prologue staging (order within a tile is irrelevant for the vm gate)
  STAGE_P1(srcA, srcB1, srcB3, lds, 0);
  STAGE_P2(srcA, srcB1, srcB3, lds, 0);
  STAGE_P1(srcA, srcB1, srcB3, lds + 32768, (size_t)64);
  STAGE_P2(srcA, srcB1, srcB3, lds + 32768, (size_t)64);
  STAGE_P1(srcA, srcB1, srcB3, lds + 65536, (size_t)128);
  STAGE_P2(srcA, srcB1, srcB3, lds + 65536, (size_t)128);
  WAIT_VM8();          // tile 0 landed (own share); barrier makes it global
  FENCE(); BAR();

  const int sx2 = (l31 >> 1) & 3;
  const int aoff  = (wr * 128 + l31) * 64 + ((hi ^ sx2) * 16);
  const int boff1 = 16384 + (wc * 32 + l31) * 64 + ((hi ^ sx2) * 16);
  const int boff3 = boff1 + 8192;
  const int kx0 = wodd ? 32 : 0;   // set0 kh-half (staggered by wave parity)
  const int kx1 = kx0 ^ 32;        // set1 kh-half

  i32x16 acc[4][2] = {};         // [m][B1|B3]
  i32x4 a0[4], b10, b30;         // set0 frags (kh = kx0)
  i32x4 a1[4], b11, b31;         // set1 frags (kh = kx1)

  // preload set0 = (tile 0, kx0)
#pragma unroll
  for (int m = 0; m < 4; ++m)
    a0[m] = *reinterpret_cast<const i32x4*>(lds + (aoff ^ kx0) + m * 2048);
  b10 = *reinterpret_cast<const i32x4*>(lds + (boff1 ^ kx0));
  b30 = *reinterpret_cast<const i32x4*>(lds + (boff3 ^ kx0));

#define MFMA8(ar, b1r, b3r)                                                   \
  acc[0][0] = __builtin_amdgcn_mfma_i32_32x32x32_i8(ar[0], b1r, acc[0][0], 0, 0, 0); \
  acc[0][1] = __builtin_amdgcn_mfma_i32_32x32x32_i8(ar[0], b3r, acc[0][1], 0, 0, 0); \
  acc[1][0] = __builtin_amdgcn_mfma_i32_32x32x32_i8(ar[1], b1r, acc[1][0], 0, 0, 0); \
  acc[1][1] = __builtin_amdgcn_mfma_i32_32x32x32_i8(ar[1], b3r, acc[1][1], 0, 0, 0); \
  acc[2][0] = __builtin_amdgcn_mfma_i32_32x32x32_i8(ar[2], b1r, acc[2][0], 0, 0, 0); \
  acc[2][1] = __builtin_amdgcn_mfma_i32_32x32x32_i8(ar[2], b3r, acc[2][1], 0, 0, 0); \
  acc[3][0] = __builtin_amdgcn_mfma_i32_32x32x32_i8(ar[3], b1r, acc[3][0], 0, 0, 0); \
  acc[3][1] = __builtin_amdgcn_mfma_i32_32x32x32_i8(ar[3], b3r, acc[3][1], 0, 0, 0)

  // ---- main loop: groups of 4 tiles, slot index = unroll constant ----
  int kb = 0;
  for (; kb < NT - 4; kb += 4) {
    const char* pA  = srcA  + (size_t)kb * 64;
    const char* pB1 = srcB1 + (size_t)kb * 64;
    const char* pB3 = srcB3 + (size_t)kb * 64;
#pragma unroll
    for (int s = 0; s < 4; ++s) {
      const char* sl = lds + s * 32768;                 // slot of tile kb+s
      const char* sn = lds + (((s + 1) & 3) * 32768);   // slot of tile kb+s+1
      char* sp = lds + (((s + 3) & 3) * 32768);         // stage dest slot
      const int ko = (s + 3) * 64;                      // folds into DMA imm

      // ---- P1: issue set1 reads; stage half; wait set0; MFMA set0 ----
      a1[0] = *reinterpret_cast<const i32x4*>(sl + (aoff ^ kx1));
      a1[1] = *reinterpret_cast<const i32x4*>(sl + (aoff ^ kx1) + 2048);
      a1[2] = *reinterpret_cast<const i32x4*>(sl + (aoff ^ kx1) + 4096);
      a1[3] = *reinterpret_cast<const i32x4*>(sl + (aoff ^ kx1) + 6144);
      b11 = *reinterpret_cast<const i32x4*>(sl + (boff1 ^ kx1));
      b31 = *reinterpret_cast<const i32x4*>(sl + (boff3 ^ kx1));
      STAGE_P1(pA, pB1, pB3, sp, ko);
      WAIT_LGKM(6); SFENCE();
      PRIO1(); MFMA8(a0, b10, b30); PRIO0();

      // ---- P2: stage other half; vm gate; drain; BAR; next set0; MFMA ----
      STAGE_P2(pA, pB1, pB3, sp, ko);
      WAIT_VM8();
      WAIT_LGKM(0);
      FENCE(); BAR();
      a0[0] = *reinterpret_cast<const i32x4*>(sn + (aoff ^ kx0));
      a0[1] = *reinterpret_cast<const i32x4*>(sn + (aoff ^ kx0) + 2048);
      a0[2] = *reinterpret_cast<const i32x4*>(sn + (aoff ^ kx0) + 4096);
      a0[3] = *reinterpret_cast<const i32x4*>(sn + (aoff ^ kx0) + 6144);
      b10 = *reinterpret_cast<const i32x4*>(sn + (boff1 ^ kx0));
      b30 = *reinterpret_cast<const i32x4*>(sn + (boff3 ^ kx0));
      SFENCE();
      PRIO1(); MFMA8(a1, b11, b31); PRIO0();
    }
  }

  // ---- tail: last 4 tiles, generic body ----
  for (int k = kb; k < NT; ++k) {
    const char* sl = lds + (k & 3) * 32768;
    const bool pf = (k + 3 < NT);

    a1[0] = *reinterpret_cast<const i32x4*>(sl + (aoff ^ kx1));
    a1[1] = *reinterpret_cast<const i32x4*>(sl + (aoff ^ kx1) + 2048);
    a1[2] = *reinterpret_cast<const i32x4*>(sl + (aoff ^ kx1) + 4096);
    a1[3] = *reinterpret_cast<const i32x4*>(sl + (aoff ^ kx1) + 6144);
    b11 = *reinterpret_cast<const i32x4*>(sl + (boff1 ^ kx1));
    b31 = *reinterpret_cast<const i32x4*>(sl + (boff3 ^ kx1));
    if (pf) {
      char* sp = lds + (((k + 3) & 3) * 32768);
      STAGE_P1(srcA, srcB1, srcB3, sp, (size_t)(k + 3) * 64);
    }
    WAIT_LGKM(6); SFENCE();
    PRIO1(); MFMA8(a0, b10, b30); PRIO0();

    if (pf) {
      char* sp = lds + (((k + 3) & 3) * 32768);
      STAGE_P2(srcA, srcB1, srcB3, sp, (size_t)(k + 3) * 64);
      WAIT_VM8();
    } else if (k == NT - 3) {
      WAIT_VM4();
    } else if (k == NT - 2) {
      WAIT_VM0();
    }
    WAIT_LGKM(0);
    FENCE(); BAR();
    if (k + 1 < NT) {
      const char* sn = lds + ((k + 1) & 3) * 32768;
      a0[0] = *reinterpret_cast<const i32x4*>(sn + (aoff ^ kx0));
      a0[1] = *reinterpret_cast<const i32x4*>(sn + (aoff ^ kx0) + 2048);
      a0[2] = *reinterpret_cast<const i32x4*>(sn + (aoff ^ kx0) + 4096);
      a0[3] = *reinterpret_cast<const i32x4*>(sn + (aoff ^ kx0) + 6144);
      b10 = *reinterpret_cast<const i32x4*>(sn + (boff1 ^ kx0));
      b30 = *reinterpret_cast<const i32x4*>(sn + (boff3 ^ kx0));
    }
    SFENCE();
    PRIO1(); MFMA8(a1, b11, b31); PRIO0();
  }
#undef MFMA8
#undef STAGE_P1
#undef STAGE_P2

  // ---- epilogue: dequant + SwiGLU -> bf16 (verified R4-R10) ----
  const int ocol = bcol + wc * 32 + l31;
  const int rowb = brow + wr * 128 + 4 * hi;
  const float sw1c = sw1[ocol], sw3c = sw3[ocol];
#pragma unroll
  for (int m = 0; m < 4; ++m) {
#pragma unroll
    for (int rq = 0; rq < 4; ++rq) {
      const int r0 = rowb + m * 32 + 8 * rq;
      const f32x4 sx4 = *reinterpret_cast<const f32x4*>(sx + r0);
#pragma unroll
      for (int j = 0; j < 4; ++j) {
        float y1 = (float)acc[m][0][rq * 4 + j] * (sx4[j] * sw1c);
        float y3 = (float)acc[m][1][rq * 4 + j] * (sx4[j] * sw3c);
        float hv = (y1 / (1.f + __expf(-y1))) * y3;
        H[(size_t)(r0 + j) * N + ocol] = f2bf(hv);
      }
    }
  }
}

// bf16 GEMM: C = A @ B^T (fp32 out). Tile 256x256, BK=32, 32x32x16 MFMA,
// R9 schedule + wave kh/stage stagger. Stored chunk = q ^ ((r>>1)&3).
__global__ __launch_bounds__(512, 2)
void gemm_bf16_kernel(const unsigned short* __restrict__ A,
                      const unsigned short* __restrict__ B,
                      float* __restrict__ C, int M, int N, int K) {
  __shared__ alignas(1024) unsigned short lds[65536];  // 4 slots x 32 KiB

  int bx = blockIdx.x, by = blockIdx.y;
  xcd_swizzle(bx, by, gridDim.x, gridDim.y);
  const int brow = by * 256, bcol = bx * 256;

  const int t = threadIdx.x, lane = t & 63, w = t >> 6;
  const int wr = w >> 2, wc = w & 3;
  const int l31 = lane & 31, hi = lane >> 5;
  const bool wodd = (w & 1);
  const int NT = K >> 5;   // BK=32

  const int rS = t >> 2;
  const int cS = ((t & 3) ^ ((t >> 3) & 3)) * 8;   // sh units
  const unsigned short* srcA = A + (size_t)(brow + rS) * K + cS;
  const unsigned short* srcB = B + (size_t)(bcol + rS) * K + cS;

#define STAGE_P1(pA_, pB_, sp, ko)                                            \
  if (!wodd) {                                                                \
    GLOAD_LDS16((pA_) + (ko), (sp) + t * 8);                                  \
    GLOAD_LDS16((pA_) + (size_t)128 * K + (ko), (sp) + 4096 + t * 8);         \
  } else {                                                                    \
    GLOAD_LDS16((pB_) + (ko), (sp) + 8192 + t * 8);                           \
    GLOAD_LDS16((pB_) + (size_t)128 * K + (ko), (sp) + 12288 + t * 8);        \
  }
#define STAGE_P2(pA_, pB_, sp, ko)                                            \
  if (wodd) {                                                                 \
    GLOAD_LDS16((pA_) + (ko), (sp) + t * 8);                                  \
    GLOAD_LDS16((pA_) + (size_t)128 * K + (ko), (sp) + 4096 + t * 8);         \
  } else {                                                                    \
    GLOAD_LDS16((pB_) + (ko), (sp) + 8192 + t * 8);                           \
    GLOAD_LDS16((pB_) + (size_t)128 * K + (ko), (sp) + 12288 + t * 8);        \
  }

  STAGE_P1(srcA, srcB, lds, 0);
  STAGE_P2(srcA, srcB, lds, 0);
  STAGE_P1(srcA, srcB, lds + 16384, (size_t)32);
  STAGE_P2(srcA, srcB, lds + 16384, (size_t)32);
  STAGE_P1(srcA, srcB, lds + 32768, (size_t)64);
  STAGE_P2(srcA, srcB, lds + 32768, (size_t)64);
  WAIT_VM8();
  FENCE(); BAR();

  const int sx2 = (l31 >> 1) & 3;
  const int aoff  = (wr * 128 + l31) * 32 + ((hi ^ sx2) * 8);
  const int boff0 = 8192 + (wc * 64 + l31) * 32 + ((hi ^ sx2) * 8);
  const int boff1b = boff0 + 1024;
  const int kx0 = wodd ? 16 : 0;   // sh units (16 sh = 32 B)
  const int kx1 = kx0 ^ 16;

  f32x16 acc[4][2] = {};
  bf16x8 a0[4], b00, b01;    // set0 (kh = kx0)
  bf16x8 a1[4], b10, b11;    // set1 (kh = kx1)

#pragma unroll
  for (int m = 0; m < 4; ++m)
    a0[m] = *reinterpret_cast<const bf16x8*>(&lds[(aoff ^ kx0) + m * 1024]);
  b00 = *reinterpret_cast<const bf16x8*>(&lds[boff0 ^ kx0]);
  b01 = *reinterpret_cast<const bf16x8*>(&lds[boff1b ^ kx0]);

#define MFMA8(ar, bx0, bx1)                                                   \
  acc[0][0] = __builtin_amdgcn_mfma_f32_32x32x16_bf16(ar[0], bx0, acc[0][0], 0, 0, 0); \
  acc[0][1] = __builtin_amdgcn_mfma_f32_32x32x16_bf16(ar[0], bx1, acc[0][1], 0, 0, 0); \
  acc[1][0] = __builtin_amdgcn_mfma_f32_32x32x16_bf16(ar[1], bx0, acc[1][0], 0, 0, 0); \
  acc[1][1] = __builtin_amdgcn_mfma_f32_32x32x16_bf16(ar[1], bx1, acc[1][1], 0, 0, 0); \
  acc[2][0] = __builtin_amdgcn_mfma_f32_32x32x16_bf16(ar[2], bx0, acc[2][0], 0, 0, 0); \
  acc[2][1] = __builtin_amdgcn_mfma_f32_32x32x16_bf16(ar[2], bx1, acc[2][1], 0, 0, 0); \
  acc[3][0] = __builtin_amdgcn_mfma_f32_32x32x16_bf16(ar[3], bx0, acc[3][0], 0, 0, 0); \
  acc[3][1] = __builtin_amdgcn_mfma_f32_32x32x16_bf16(ar[3], bx1, acc[3][1], 0, 0, 0)

  int kb = 0;
  for (; kb < NT - 4; kb += 4) {
    const unsigned short* pA = srcA + (size_t)kb * 32;
    const unsigned short* pB = srcB + (size_t)kb * 32;
#pragma unroll
    for (int s = 0; s < 4; ++s) {
      const unsigned short* sl = lds + s * 16384;
      const unsigned short* sn = lds + (((s + 1) & 3) * 16384);
      unsigned short* sp = lds + (((s + 3) & 3) * 16384);
      const int ko = (s + 3) * 32;

      // ---- P1 ----
      a1[0] = *reinterpret_cast<const bf16x8*>(sl + (aoff ^ kx1));
      a1[1] = *reinterpret_cast<const bf16x8*>(sl + (aoff ^ kx1) + 1024);
      a1[2] = *reinterpret_cast<const bf16x8*>(sl + (aoff ^ kx1) + 2048);
      a1[3] = *reinterpret_cast<const bf16x8*>(sl + (aoff ^ kx1) + 3072);
      b10 = *reinterpret_cast<const bf16x8*>(sl + (boff0 ^ kx1));
      b11 = *reinterpret_cast<const bf16x8*>(sl + (boff1b ^ kx1));
      STAGE_P1(pA, pB, sp, ko);
      WAIT_LGKM(6); SFENCE();
      PRIO1(); MFMA8(a0, b00, b01); PRIO0();

      // ---- P2 ----
      STAGE_P2(pA, pB, sp, ko);
      WAIT_VM8();
      WAIT_LGKM(0);
      FENCE(); BAR();
      a0[0] = *reinterpret_cast<const bf16x8*>(sn + (aoff ^ kx0));
      a0[1] = *reinterpret_cast<const bf16x8*>(sn + (aoff ^ kx0) + 1024);
      a0[2] = *reinterpret_cast<const bf16x8*>(sn + (aoff ^ kx0) + 2048);
      a0[3] = *reinterpret_cast<const bf16x8*>(sn + (aoff ^ kx0) + 3072);
      b00 = *reinterpret_cast<const bf16x8*>(sn + (boff0 ^ kx0));
      b01 = *reinterpret_cast<const bf16x8*>(sn + (boff1b ^ kx0));
      SFENCE();
      PRIO1(); MFMA8(a1, b10, b11); PRIO0();
    }
  }

  for (int k = kb; k < NT; ++k) {
    const unsigned short* sl = &lds[(k & 3) * 16384];
    const bool pf = (k + 3 < NT);

    a1[0] = *reinterpret_cast<const bf16x8*>(sl + (aoff ^ kx1));
    a1[1] = *reinterpret_cast<const bf16x8*>(sl + (aoff ^ kx1) + 1024);
    a1[2] = *reinterpret_cast<const bf16x8*>(sl + (aoff ^ kx1) + 2048);
    a1[3] = *reinterpret_cast<const bf16x8*>(sl + (aoff ^ kx1) + 3072);
    b10 = *reinterpret_cast<const bf16x8*>(sl + (boff0 ^ kx1));
    b11 = *reinterpret_cast<const bf16x8*>(sl + (boff1b ^ kx1));
    if (pf) {
      unsigned short* sp = lds + (((k + 3) & 3) * 16384);
      STAGE_P1(srcA, srcB, sp, (size_t)(k + 3) * 32);
    }
    WAIT_LGKM(6); SFENCE();
    PRIO1(); MFMA8(a0, b00, b01); PRIO0();

    if (pf) {
      unsigned short* sp = lds + (((k + 3) & 3) * 16384);
      STAGE_P2(srcA, srcB, sp, (size_t)(k + 3) * 32);
      WAIT_VM8();
    } else if (k == NT - 3) {
      WAIT_VM4();
    } else if (k == NT - 2) {
      WAIT_VM0();
    }
    WAIT_LGKM(0);
    FENCE(); BAR();
    if (k + 1 < NT) {
      const unsigned short* sn = &lds[((k + 1) & 3) * 16384];
      a0[0] = *reinterpret_cast<const bf16x8*>(sn + (aoff ^ kx0));
      a0[1] = *reinterpret_cast<const bf16x8*>(sn + (aoff ^ kx0) + 1024);
      a0[2] = *reinterpret_cast<const bf16x8*>(sn + (aoff ^ kx0) + 2048);
      a0[3] = *reinterpret_cast<const bf16x8*>(sn + (aoff ^ kx0) + 3072);
      b00 = *reinterpret_cast<const bf16x8*>(sn + (boff0 ^ kx0));
      b01 = *reinterpret_cast<const bf16x8*>(sn + (boff1b ^ kx0));
    }
    SFENCE();
    PRIO1(); MFMA8(a1, b10, b11); PRIO0();
  }
#undef MFMA8
#undef STAGE_P1
#undef STAGE_P2

  const int ocol = bcol + wc * 64 + l31;
  const int rowb = brow + wr * 128 + 4 * hi;
#pragma unroll
  for (int m = 0; m < 4; ++m)
#pragma unroll
    for (int n = 0; n < 2; ++n)
#pragma unroll
      for (int rq = 0; rq < 4; ++rq)
#pragma unroll
        for (int j = 0; j < 4; ++j)
          C[(size_t)(rowb + m * 32 + 8 * rq + j) * N + (ocol + n * 32)] =
              acc[m][n][rq * 4 + j];
}

// ------------------------------ launch -------------------------------------

extern "C" void kernel_launch(void* const* d_in, const int* in_sizes, int n_in,
                              void* d_out, int out_size, void* d_ws,
                              size_t ws_size, hipStream_t stream) {
  const float* x  = (const float*)d_in[0];
  const float* w1 = (const float*)d_in[1];
  const float* w2 = (const float*)d_in[2];
  const float* w3 = (const float*)d_in[3];
  float* out = (float*)d_out;

  const int DIM = 4096, HID = 8192;
  const int M = in_sizes[0] / DIM;  // 8192

  char* xq  = (char*)d_ws;                              // M*DIM    (32 MB)
  char* w1q = xq + (size_t)M * DIM;                     // HID*DIM  (32 MB)
  char* w3q = w1q + (size_t)HID * DIM;                  // HID*DIM  (32 MB)
  unsigned short* w2b = (unsigned short*)(w3q + (size_t)HID * DIM);  // 64 MB
  unsigned short* h = w2b + (size_t)DIM * HID;          // M*HID bf16 (128 MB)
  float* sx  = (float*)(h + (size_t)M * HID);           // M
  float* sw1 = sx + M;                                  // HID
  float* sw3 = sw1 + HID;                               // HID

  quant_rows_i8_sp<4><<<HID, 256, 0, stream>>>(w1, w1q, sw1, 1e-6f);
  quant_rows_i8_sp<4><<<HID, 256, 0, stream>>>(w3, w3q, sw3, 1e-6f);
  quant_rows_i8_sp<4><<<M, 256, 0, stream>>>(x, xq, sx, 1e-30f);
  quant_rows_bf16_sp<8><<<DIM, 256, 0, stream>>>(w2, w2b);

  gemm_i8_swiglu_kernel<<<dim3(HID / 128, M / 256), 512, 0, stream>>>(
      xq, w1q, w3q, sx, sw1, sw3, h, M, HID, DIM);
  gemm_bf16_kernel<<<dim3(DIM / 256, M / 256), 512, 0, stream>>>(
      h, w2b, out, M, DIM, HID);
}